// Round 4
// baseline (495.306 us; speedup 1.0000x reference)
//
#include <hip/hip_runtime.h>
#include <hip/hip_bf16.h>

#define DD 128
#define KK 256
#define TS 256        // samples per stage-3 tile (8 waves x 32-row m-tiles)
#define ROWB 136      // padded LDS row stride (bf16): uniform 8/bank for b128 frag reads
#define SPB1 1024     // samples per stage-1 block

typedef __attribute__((ext_vector_type(8))) short short8;
typedef __attribute__((ext_vector_type(16))) float f32x16;

static __device__ __forceinline__ unsigned short f2bf(float f) {
    unsigned int u = __float_as_uint(f);
    return (unsigned short)((u + 0x7fffu + ((u >> 16) & 1u)) >> 16);   // RNE
}

template<int CTRL>
static __device__ __forceinline__ float mdpp_max(float x) {
    const int xi = __builtin_bit_cast(int, x);
    const int yi = __builtin_amdgcn_update_dpp(xi, xi, CTRL, 0xF, 0xF, false);
    return fmaxf(x, __builtin_bit_cast(float, yi));
}
// max over each 32-lane group: 4 DPP steps (within 16) + xor16 swizzle
static __device__ __forceinline__ float redmax32(float x) {
    x = mdpp_max<0xB1>(x);    // quad_perm {1,0,3,2}  = xor1
    x = mdpp_max<0x4E>(x);    // quad_perm {2,3,0,1}  = xor2
    x = mdpp_max<0x124>(x);   // row_ror:4
    x = mdpp_max<0x128>(x);   // row_ror:8  -> full 16-lane max
    const int yi = __builtin_amdgcn_ds_swizzle(__builtin_bit_cast(int, x), 0x401F); // xor16
    return fmaxf(x, __builtin_bit_cast(float, yi));
}

// ---------------- stage 1: counting-sort gather; emits partials, Xbf16, x2 ----------------
// MODE 0: per-block partial slot + Xbf + x2g.  MODE 2: global-atomic merge, no side-products.
template<int MODE>
__global__ __launch_bounds__(1024) void k_stage1_gather(
    const float* __restrict__ X, const int* __restrict__ labels,
    float* __restrict__ partial, unsigned int* __restrict__ Xbf,
    float* __restrict__ x2g)
{
    __shared__ int lab[SPB1];
    __shared__ int idx[SPB1];
    __shared__ int hist[KK];
    __shared__ int start[KK + 1];
    __shared__ int cursor[KK];

    const int tid  = threadIdx.x;
    const int lane = tid & 63;
    const int wave = tid >> 6;
    const int base = blockIdx.x * SPB1;

    if (tid < KK) hist[tid] = 0;
    __syncthreads();
    {
        const int l = labels[base + tid];
        lab[tid] = l;
        atomicAdd(&hist[l], 1);
    }
    __syncthreads();
    if (wave == 0) {                        // exclusive scan of 256 bins in one wave
        const int h0 = hist[4*lane], h1 = hist[4*lane+1];
        const int h2 = hist[4*lane+2], h3 = hist[4*lane+3];
        const int s = h0 + h1 + h2 + h3;
        int t = s;
#pragma unroll
        for (int d = 1; d < 64; d <<= 1) { const int u = __shfl_up(t, d); if (lane >= d) t += u; }
        const int e = t - s;
        start[4*lane]   = e;
        start[4*lane+1] = e + h0;
        start[4*lane+2] = e + h0 + h1;
        start[4*lane+3] = e + h0 + h1 + h2;
        if (lane == 63) start[KK] = t;
    }
    __syncthreads();
    if (tid < KK) cursor[tid] = start[tid];
    __syncthreads();
    {
        const int pos = atomicAdd(&cursor[lab[tid]], 1);
        idx[pos] = tid;
    }
    __syncthreads();

    // each wave gathers 16 clusters; lanes cover 128 dims as float2
    for (int c = wave; c < KK; c += 16) {
        const int s0 = start[c], s1 = start[c + 1];
        float2 acc = make_float2(0.f, 0.f);
        if (s1 > s0) {
            int n0 = idx[s0];
            float2 v = *(const float2*)(X + (size_t)(base + n0) * DD + 2 * lane);
            for (int i = s0 + 1; i < s1; ++i) {
                const int n1 = idx[i];
                const float2 v1 = *(const float2*)(X + (size_t)(base + n1) * DD + 2 * lane);
                acc.x += v.x; acc.y += v.y;
                if (MODE == 0) {
                    Xbf[(size_t)(base + n0) * (DD/2) + lane] =
                        ((unsigned)f2bf(v.y) << 16) | (unsigned)f2bf(v.x);
                    float p = v.x*v.x + v.y*v.y;
#pragma unroll
                    for (int m = 32; m > 0; m >>= 1) p += __shfl_xor(p, m);
                    if (lane == 0) x2g[base + n0] = p;
                }
                n0 = n1; v = v1;
            }
            acc.x += v.x; acc.y += v.y;
            if (MODE == 0) {
                Xbf[(size_t)(base + n0) * (DD/2) + lane] =
                    ((unsigned)f2bf(v.y) << 16) | (unsigned)f2bf(v.x);
                float p = v.x*v.x + v.y*v.y;
#pragma unroll
                for (int m = 32; m > 0; m >>= 1) p += __shfl_xor(p, m);
                if (lane == 0) x2g[base + n0] = p;
            }
        }
        if (MODE == 2) {
            atomicAdd(&partial[(size_t)c * DD + 2 * lane],     acc.x);
            atomicAdd(&partial[(size_t)c * DD + 2 * lane + 1], acc.y);
        } else {
            *(float2*)(partial + ((size_t)blockIdx.x * KK + c) * DD + 2 * lane) = acc;
        }
    }
}

// ---------------- stage 2: reduce partials, normalize (counts cancel), emit bf16 ----------------
__global__ void k_stage2(const float* __restrict__ partial, int nparts,
                         unsigned short* __restrict__ centb)
{
    const int k = blockIdx.x;
    const int t = threadIdx.x;      // 512
    const int d = t & (DD - 1);
    const int slice = t >> 7;
    float s = 0.f;
    for (int b = slice; b < nparts; b += 4)
        s += partial[((size_t)b * KK + k) * DD + d];
    __shared__ float red[4][DD];
    red[slice][d] = s;
    __syncthreads();
    float v = 0.f;
    if (t < DD) v = red[0][d] + red[1][d] + red[2][d] + red[3][d];
    float sq = v * v;
#pragma unroll
    for (int m = 32; m > 0; m >>= 1) sq += __shfl_xor(sq, m);
    __shared__ float wsum[8];
    if ((t & 63) == 0) wsum[t >> 6] = sq;
    __syncthreads();
    if (t < DD) centb[k * DD + d] = f2bf(v * rsqrtf(wsum[0] + wsum[1]));
}

// ---------------- stage 3: 32x32x16 MFMA, reg-buffered staging, DPP epilogue ----------------
// XB=1: bf16 X (Xbf) + x2g.  XB=0 fallback: fp32 X, x2 computed in-kernel.
template<int XB>
__global__ __launch_bounds__(512, 2) void k_stage3(
    const float* __restrict__ Xf, const unsigned int* __restrict__ Xbf,
    const int* __restrict__ labels, const float* __restrict__ x2g,
    const unsigned short* __restrict__ centb,
    const float* __restrict__ hbias, float* __restrict__ loss, int spb)
{
    __shared__ __align__(16) unsigned short Cl[KK * ROWB];  // 69632 B
    __shared__ __align__(16) unsigned short Xl[TS * ROWB];  // 69632 B
    __shared__ __align__(16) int   labsS[TS];
    __shared__ __align__(16) float x2S[TS];
    __shared__ float lred[16];

    const int tid  = threadIdx.x;
    const int lane = tid & 63;
    const int wave = tid >> 6;        // 0..7 = m-tile (32 samples each)
    const int l31  = lane & 31;
    const int half = lane >> 5;       // k-group
    const int base = blockIdx.x * spb;

    const float hb = *hbias;
    const float bias = (hb > 20.f) ? hb : log1pf(__expf(hb));
    const float pos_bias = bias;
    const float neg_bias = 9.f * bias + 0.05f;

    // stage all centroids once
    {
        const uint4* csrc = (const uint4*)centb;
        for (int c = tid; c < KK * DD / 8; c += 512) {
            const int row = c >> 4, col = (c & 15) << 3;
            *(uint4*)(&Cl[row * ROWB + col]) = csrc[c];
        }
    }

    // preload tile 0 staging registers (bf16 path)
    uint4 buf[8];
    int labr = 0; float x2r = 0.f;
    if (XB) {
        const uint4* xs = (const uint4*)Xbf;
        const size_t gb = (size_t)base << 4;           // 16 uint4 chunks per row
#pragma unroll
        for (int i = 0; i < 8; ++i) buf[i] = xs[gb + tid + (i << 9)];
        if (tid < TS) { labr = labels[base + tid]; x2r = x2g[base + tid]; }
    }

    float pos_acc = 0.f, neg_acc = 0.f;

    for (int t0 = 0; t0 < spb; t0 += TS) {
        __syncthreads();   // prior tile's LDS reads done (also covers Cl staging)

        if (XB) {
            // write prefetched regs -> Xl (padded rows)
#pragma unroll
            for (int i = 0; i < 8; ++i) {
                const int c = tid + (i << 9);
                const int row = c >> 4, col = (c & 15) << 3;
                *(uint4*)(&Xl[row * ROWB + col]) = buf[i];
            }
            if (tid < TS) { labsS[tid] = labr; x2S[tid] = x2r; }
            if (t0 + TS < spb) {   // prefetch next tile during this tile's compute
                const uint4* xs = (const uint4*)Xbf;
                const size_t gb = (size_t)(base + t0 + TS) << 4;
#pragma unroll
                for (int i = 0; i < 8; ++i) buf[i] = xs[gb + tid + (i << 9)];
                if (tid < TS) {
                    labr = labels[base + t0 + TS + tid];
                    x2r  = x2g[base + t0 + TS + tid];
                }
            }
            __syncthreads();   // Xl ready
        } else {
            // fallback: synchronous fp32 staging + in-kernel x2
            const float4* xsrc = (const float4*)(Xf + (size_t)(base + t0) * DD);
            for (int c = tid; c < TS * DD / 4; c += 512) {
                const int row = c >> 5, col = (c & 31) << 2;
                const float4 v = xsrc[c];
                ushort4 pk = make_ushort4(f2bf(v.x), f2bf(v.y), f2bf(v.z), f2bf(v.w));
                *(ushort4*)(&Xl[row * ROWB + col]) = pk;
            }
            if (tid < TS) labsS[tid] = labels[base + t0 + tid];
            __syncthreads();
            {   // x2 from staged bf16: thread pair per sample
                const int s  = tid >> 1, h = tid & 1;
                float p = 0.f;
#pragma unroll
                for (int c = 0; c < 8; ++c) {
                    const short8 w = *(const short8*)(&Xl[s * ROWB + (h << 6) + (c << 3)]);
#pragma unroll
                    for (int j = 0; j < 8; ++j) {
                        const float e = __uint_as_float(((unsigned)(unsigned short)w[j]) << 16);
                        p = fmaf(e, e, p);
                    }
                }
                p += __shfl_xor(p, 1);
                if (h == 0 && s < TS) x2S[s] = p;
            }
            __syncthreads();
        }

        // A-fragments: this wave's 32 samples, all of K
        short8 af[8];
        const int arow = (wave << 5) + l31;
#pragma unroll
        for (int s = 0; s < 8; ++s)
            af[s] = *(const short8*)(&Xl[arow * ROWB + (s << 4) + (half << 3)]);

        // labels/x2 for this lane's 16 C-rows: row = (r&3) + 8*(r>>2) + 4*half
        int la[16]; float xv[16];
#pragma unroll
        for (int g = 0; g < 4; ++g) {
            const int r0 = (wave << 5) + (g << 3) + (half << 2);
            const int4   L  = *(const int4*)(&labsS[r0]);
            const float4 Xq = *(const float4*)(&x2S[r0]);
            la[4*g+0] = L.x;  la[4*g+1] = L.y;  la[4*g+2] = L.z;  la[4*g+3] = L.w;
            xv[4*g+0] = Xq.x; xv[4*g+1] = Xq.y; xv[4*g+2] = Xq.z; xv[4*g+3] = Xq.w;
        }

        float posc[16], negc[16];
#pragma unroll
        for (int r = 0; r < 16; ++r) { posc[r] = -1e30f; negc[r] = -1e30f; }

#pragma unroll
        for (int t = 0; t < 8; ++t) {          // 32-cluster t-tiles
            f32x16 acc;
#pragma unroll
            for (int r = 0; r < 16; ++r) acc[r] = 0.f;
#pragma unroll
            for (int s = 0; s < 8; ++s) {
                const short8 bf = *(const short8*)(&Cl[(t*32 + l31) * ROWB + (s << 4) + (half << 3)]);
                acc = __builtin_amdgcn_mfma_f32_32x32x16_bf16(af[s], bf, acc, 0, 0, 0);
            }
            const int myc = (t << 5) + l31;    // this lane's cluster column
#pragma unroll
            for (int r = 0; r < 16; ++r) {
                const float v = acc[r];
                const bool own = (la[r] == myc);
                negc[r] = own ? negc[r] : fmaxf(negc[r], v);
                posc[r] = own ? v : posc[r];
            }
        }

        // reduce over 32 cluster-lanes per half-group; lane l31==r accumulates row r
#pragma unroll
        for (int r = 0; r < 16; ++r) {
            const float p  = redmax32(posc[r]);
            const float nm = redmax32(negc[r]);
            const float pd = xv[r] + 1.f - 2.f * p;    // ||c||^2 == 1
            const float nd = xv[r] + 1.f - 2.f * nm;   // min dist <=> max dot
            if (l31 == r) {
                pos_acc += fmaxf(pd - pos_bias, 0.f);
                neg_acc += fmaxf(neg_bias - nd, 0.f);
            }
        }
    }

#pragma unroll
    for (int m = 32; m > 0; m >>= 1) {
        pos_acc += __shfl_xor(pos_acc, m);
        neg_acc += __shfl_xor(neg_acc, m);
    }
    if (lane == 0) { lred[wave] = pos_acc; lred[8 + wave] = neg_acc; }
    __syncthreads();
    if (tid == 0) {
        float p = 0.f, n = 0.f;
#pragma unroll
        for (int w = 0; w < 8; ++w) { p += lred[w]; n += lred[8 + w]; }
        atomicAdd(&loss[0], p);
        atomicAdd(&loss[1], n);
    }
}

__global__ void k_final(const float* __restrict__ loss, float* __restrict__ out, float invN)
{
    if (threadIdx.x == 0) {
        out[0] = 4.0f * loss[0] * invN;
        out[1] = loss[1] * invN;
    }
}

extern "C" void kernel_launch(void* const* d_in, const int* in_sizes, int n_in,
                              void* d_out, int out_size, void* d_ws, size_t ws_size,
                              hipStream_t stream)
{
    const float* X      = (const float*)d_in[0];
    // d_in[1] (scores) is dead in the reference forward — never read.
    const int*   labels = (const int*)d_in[2];
    const float* hbias  = (const float*)d_in[3];
    float* out = (float*)d_out;
    const int N = in_sizes[0] / DD;
    const int G = N / SPB1;                   // 256 blocks

    char* ws = (char*)d_ws;
    const size_t offC   = 256;
    const size_t offX2  = offC  + (size_t)KK * DD * 2;     // centb: 64 KiB
    const size_t offXbf = offX2 + (size_t)N * 4;           // x2g:   1 MiB
    const size_t offP   = offXbf + (size_t)N * DD * 2;     // Xbf:  64 MiB
    const size_t szPart = (size_t)G * KK * DD * 4;         // 32 MiB

    float*          loss    = (float*)ws;
    unsigned short* centb   = (unsigned short*)(ws + offC);
    float*          x2g     = (float*)(ws + offX2);
    unsigned int*   Xbf     = (unsigned int*)(ws + offXbf);
    float*          partial = (float*)(ws + offP);

    const int full = (ws_size >= offP + szPart) ? 1 : 0;
    const int nparts = full ? G : 1;
    if (!full) partial = (float*)(ws + offC + (size_t)KK * DD * 2);

    hipMemsetAsync(loss, 0, 2 * sizeof(float), stream);
    if (!full) hipMemsetAsync(partial, 0, (size_t)KK * DD * 4, stream);

    if (full) k_stage1_gather<0><<<G, 1024, 0, stream>>>(X, labels, partial, Xbf, x2g);
    else      k_stage1_gather<2><<<G, 1024, 0, stream>>>(X, labels, partial, nullptr, nullptr);

    k_stage2<<<KK, 512, 0, stream>>>(partial, nparts, centb);

    if (full) k_stage3<1><<<G, 512, 0, stream>>>(nullptr, Xbf, labels, x2g, centb, hbias, loss, N / G);
    else      k_stage3<0><<<G, 512, 0, stream>>>(X, nullptr, labels, nullptr, centb, hbias, loss, N / G);

    k_final<<<1, 64, 0, stream>>>(loss, out, 1.0f / (float)N);
}

// Round 5
// 465.394 us; speedup vs baseline: 1.0643x; 1.0643x over previous
//
#include <hip/hip_runtime.h>
#include <hip/hip_bf16.h>

#define DD 128
#define KK 256
#define TS 256        // samples per stage-3 tile
#define ROWB 136      // padded LDS row stride (bf16 elems)
#define SPB1 1024     // samples per stage-1 block

typedef __attribute__((ext_vector_type(8))) short short8;
typedef __attribute__((ext_vector_type(4))) float f32x4;

static __device__ __forceinline__ unsigned short f2bf(float f) {
    unsigned int u = __float_as_uint(f);
    return (unsigned short)((u + 0x7fffu + ((u >> 16) & 1u)) >> 16);   // RNE
}
static __device__ __forceinline__ float bf2f(unsigned short h) {
    return __uint_as_float(((unsigned int)h) << 16);
}

// ---------------- stage 1: counting-sort gather, 8-deep load pipeline ----------------
// MODE 0: per-block partial slot.  MODE 2: global-atomic merge (tiny-ws fallback).
template<int MODE>
__global__ __launch_bounds__(1024) void k_stage1_gather(
    const float* __restrict__ X, const int* __restrict__ labels,
    float* __restrict__ partial)
{
    __shared__ int lab[SPB1];
    __shared__ int idx[SPB1];
    __shared__ int hist[KK];
    __shared__ int start[KK + 1];
    __shared__ int cursor[KK];

    const int tid  = threadIdx.x;
    const int lane = tid & 63;
    const int wave = tid >> 6;
    const int base = blockIdx.x * SPB1;

    if (tid < KK) hist[tid] = 0;
    __syncthreads();
    {
        const int l = labels[base + tid];
        lab[tid] = l;
        atomicAdd(&hist[l], 1);
    }
    __syncthreads();
    if (wave == 0) {                        // exclusive scan of 256 bins in one wave
        const int h0 = hist[4*lane], h1 = hist[4*lane+1];
        const int h2 = hist[4*lane+2], h3 = hist[4*lane+3];
        const int s = h0 + h1 + h2 + h3;
        int t = s;
#pragma unroll
        for (int d = 1; d < 64; d <<= 1) { const int u = __shfl_up(t, d); if (lane >= d) t += u; }
        const int e = t - s;
        start[4*lane]   = e;
        start[4*lane+1] = e + h0;
        start[4*lane+2] = e + h0 + h1;
        start[4*lane+3] = e + h0 + h1 + h2;
        if (lane == 63) start[KK] = t;
    }
    __syncthreads();
    if (tid < KK) cursor[tid] = start[tid];
    __syncthreads();
    {
        const int pos = atomicAdd(&cursor[lab[tid]], 1);
        idx[pos] = tid;
    }
    __syncthreads();

    // wave w owns contiguous clusters [16w, 16w+16); flat member walk, 8 loads in flight
    const int c1 = (wave << 4) + 16;
    int c = wave << 4;
    const int s0 = start[c], s1 = start[c1];
    const int cnt = s1 - s0;

    float2 pf[8];
#pragma unroll
    for (int j = 0; j < 8; ++j)
        if (j < cnt)
            pf[j] = *(const float2*)(X + (size_t)(base + idx[s0 + j]) * DD + 2 * lane);

    float2 acc = make_float2(0.f, 0.f);
    int i = 0;
    for (; i + 8 <= cnt; i += 8) {
#pragma unroll
        for (int j = 0; j < 8; ++j) {
            const float2 v = pf[j];
            if (i + j + 8 < cnt)
                pf[j] = *(const float2*)(X + (size_t)(base + idx[s0 + i + j + 8]) * DD + 2 * lane);
            while (s0 + i + j >= start[c + 1]) {       // wave-uniform boundary flush
                if (MODE == 2) {
                    atomicAdd(&partial[(size_t)c * DD + 2*lane],     acc.x);
                    atomicAdd(&partial[(size_t)c * DD + 2*lane + 1], acc.y);
                } else {
                    *(float2*)(partial + ((size_t)blockIdx.x * KK + c) * DD + 2*lane) = acc;
                }
                acc = make_float2(0.f, 0.f); ++c;
            }
            acc.x += v.x; acc.y += v.y;
        }
    }
#pragma unroll
    for (int j = 0; j < 8; ++j) {                       // tail (<8 rows), pf[j] = row i+j
        if (i + j < cnt) {
            const float2 v = pf[j];
            while (s0 + i + j >= start[c + 1]) {
                if (MODE == 2) {
                    atomicAdd(&partial[(size_t)c * DD + 2*lane],     acc.x);
                    atomicAdd(&partial[(size_t)c * DD + 2*lane + 1], acc.y);
                } else {
                    *(float2*)(partial + ((size_t)blockIdx.x * KK + c) * DD + 2*lane) = acc;
                }
                acc = make_float2(0.f, 0.f); ++c;
            }
            acc.x += v.x; acc.y += v.y;
        }
    }
    while (c < c1) {                                    // flush trailing (incl. empty) clusters
        if (MODE == 2) {
            atomicAdd(&partial[(size_t)c * DD + 2*lane],     acc.x);
            atomicAdd(&partial[(size_t)c * DD + 2*lane + 1], acc.y);
        } else {
            *(float2*)(partial + ((size_t)blockIdx.x * KK + c) * DD + 2*lane) = acc;
        }
        acc = make_float2(0.f, 0.f); ++c;
    }
}

// ---------------- stage 2: reduce partials, normalize (counts cancel), emit bf16 ----------------
__global__ void k_stage2(const float* __restrict__ partial, int nparts,
                         unsigned short* __restrict__ centb)
{
    const int k = blockIdx.x;
    const int t = threadIdx.x;      // 512
    const int d = t & (DD - 1);
    const int slice = t >> 7;
    float s = 0.f;
    for (int b = slice; b < nparts; b += 4)
        s += partial[((size_t)b * KK + k) * DD + d];
    __shared__ float red[4][DD];
    red[slice][d] = s;
    __syncthreads();
    float v = 0.f;
    if (t < DD) v = red[0][d] + red[1][d] + red[2][d] + red[3][d];
    float sq = v * v;
#pragma unroll
    for (int m = 32; m > 0; m >>= 1) sq += __shfl_xor(sq, m);
    __shared__ float wsum[8];
    if ((t & 63) == 0) wsum[t >> 6] = sq;
    __syncthreads();
    if (t < DD) centb[k * DD + d] = f2bf(v * rsqrtf(wsum[0] + wsum[1]));
}

// ---------------- stage 3 (R3 control, unchanged): fused X@C^T MFMA + loss ----------------
__global__ __launch_bounds__(1024, 4) void k_stage3(
    const float* __restrict__ Xf, const int* __restrict__ labels,
    const unsigned short* __restrict__ centb,
    const float* __restrict__ hbias, float* __restrict__ loss, int spb)
{
    __shared__ unsigned short Cl[KK * ROWB];
    __shared__ unsigned short Xl[TS * ROWB];
    __shared__ int   labs[TS];
    __shared__ float lred[32];

    const int tid = threadIdx.x;
    const float hb = *hbias;
    const float bias = (hb > 20.f) ? hb : log1pf(__expf(hb));
    const float pos_bias = bias;
    const float neg_bias = 9.f * bias + 0.05f;

    const uint4* csrc = (const uint4*)centb;
    for (int c = tid; c < KK * DD / 8; c += 1024) {
        const int row = c >> 4;
        const int col = (c & 15) << 3;
        *(uint4*)(&Cl[row * ROWB + col]) = csrc[c];
    }

    const int lane = tid & 63;
    const int wave = tid >> 6;       // 0..15
    const int m15  = lane & 15;
    const int q    = lane >> 4;
    const int kq   = q << 3;
    const int base = blockIdx.x * spb;
    float pos_acc = 0.f, neg_acc = 0.f;

    for (int t0 = 0; t0 < spb; t0 += TS) {
        __syncthreads();
        const float4* xsrc = (const float4*)(Xf + (size_t)(base + t0) * DD);
        for (int c = tid; c < TS * DD / 4; c += 1024) {
            const int row = c >> 5;
            const int col = (c & 31) << 2;
            const float4 v = xsrc[c];
            ushort4 pk = make_ushort4(f2bf(v.x), f2bf(v.y), f2bf(v.z), f2bf(v.w));
            *(ushort4*)(&Xl[row * ROWB + col]) = pk;
        }
        if (tid < TS) labs[tid] = labels[base + t0 + tid];
        __syncthreads();

        short8 afrag[4];
        const int arow = (wave << 4) + m15;
#pragma unroll
        for (int s = 0; s < 4; ++s)
            afrag[s] = *(const short8*)(&Xl[arow * ROWB + (s << 5) + kq]);

        float x2p = 0.f;
#pragma unroll
        for (int s = 0; s < 4; ++s)
#pragma unroll
            for (int j = 0; j < 8; ++j) {
                const float e = bf2f((unsigned short)afrag[s][j]);
                x2p = fmaf(e, e, x2p);
            }
        x2p += __shfl_xor(x2p, 16);
        x2p += __shfl_xor(x2p, 32);

        f32x4 acc[16];
#pragma unroll
        for (int t = 0; t < 16; ++t) acc[t] = (f32x4){0.f, 0.f, 0.f, 0.f};
#pragma unroll
        for (int t = 0; t < 16; ++t) {
            const int brow = (t << 4) + m15;
#pragma unroll
            for (int s = 0; s < 4; ++s) {
                const short8 bfrag = *(const short8*)(&Cl[brow * ROWB + (s << 5) + kq]);
                acc[t] = __builtin_amdgcn_mfma_f32_16x16x32_bf16(afrag[s], bfrag, acc[t], 0, 0, 0);
            }
        }

#pragma unroll
        for (int r = 0; r < 4; ++r) {
            const int ml = (wave << 4) + (q << 2) + r;
            const int l  = labs[ml];
            const float x2 = __shfl(x2p, (q << 2) + r, 16);
            float posd = -1e30f, negd = -1e30f;
#pragma unroll
            for (int t = 0; t < 16; ++t) {
                const int cl = (t << 4) + m15;
                const float v = acc[t][r];
                const bool isp = (cl == l);
                posd = isp ? v : posd;
                negd = isp ? negd : fmaxf(negd, v);
            }
#pragma unroll
            for (int m = 1; m < 16; m <<= 1) {
                posd = fmaxf(posd, __shfl_xor(posd, m));
                negd = fmaxf(negd, __shfl_xor(negd, m));
            }
            if (m15 == 0) {
                const float pd = x2 + 1.0f - 2.f * posd;
                const float nd = x2 + 1.0f - 2.f * negd;
                pos_acc += fmaxf(pd - pos_bias, 0.f);
                neg_acc += fmaxf(neg_bias - nd, 0.f);
            }
        }
    }

#pragma unroll
    for (int m = 32; m > 0; m >>= 1) {
        pos_acc += __shfl_xor(pos_acc, m);
        neg_acc += __shfl_xor(neg_acc, m);
    }
    if (lane == 0) { lred[wave] = pos_acc; lred[16 + wave] = neg_acc; }
    __syncthreads();
    if (tid == 0) {
        float p = 0.f, n = 0.f;
#pragma unroll
        for (int w = 0; w < 16; ++w) { p += lred[w]; n += lred[16 + w]; }
        atomicAdd(&loss[0], p);
        atomicAdd(&loss[1], n);
    }
}

__global__ void k_final(const float* __restrict__ loss, float* __restrict__ out, float invN)
{
    if (threadIdx.x == 0) {
        out[0] = 4.0f * loss[0] * invN;
        out[1] = loss[1] * invN;
    }
}

extern "C" void kernel_launch(void* const* d_in, const int* in_sizes, int n_in,
                              void* d_out, int out_size, void* d_ws, size_t ws_size,
                              hipStream_t stream)
{
    const float* X      = (const float*)d_in[0];
    // d_in[1] (scores) is dead in the reference forward — never read.
    const int*   labels = (const int*)d_in[2];
    const float* hbias  = (const float*)d_in[3];
    float* out = (float*)d_out;
    const int N = in_sizes[0] / DD;
    const int G = N / SPB1;                   // 256 blocks

    char* ws = (char*)d_ws;
    const size_t offC    = 256;
    const size_t offPart = offC + (size_t)KK * DD * 2;
    const size_t szPart  = (size_t)G * KK * DD * 4;    // 32 MiB

    float*          loss    = (float*)ws;
    unsigned short* centb   = (unsigned short*)(ws + offC);
    float*          partial = (float*)(ws + offPart);

    const int mode   = (ws_size >= offPart + szPart) ? 0 : 2;
    const int nparts = (mode == 2) ? 1 : G;

    hipMemsetAsync(loss, 0, 2 * sizeof(float), stream);
    if (mode == 2) hipMemsetAsync(partial, 0, (size_t)KK * DD * 4, stream);

    if (mode == 0) k_stage1_gather<0><<<G, 1024, 0, stream>>>(X, labels, partial);
    else           k_stage1_gather<2><<<G, 1024, 0, stream>>>(X, labels, partial);

    k_stage2<<<KK, 512, 0, stream>>>(partial, nparts, centb);

    k_stage3<<<G, 1024, 0, stream>>>(X, labels, centb, hbias, loss, N / G);

    k_final<<<1, 64, 0, stream>>>(loss, out, 1.0f / (float)N);
}